// Round 1
// baseline (217.789 us; speedup 1.0000x reference)
//
#include <hip/hip_runtime.h>

#define NQ 14
#define NSTATE (1 << NQ)       // 16384 amplitudes
#define NPAIR (NSTATE / 2)     // 8192 pairs per gate pass
#define NL 3
#define NGATES (NQ + NL * NQ)  // 14 RX + 42 Rot = 56
#define BT 1024                // threads per block
#define NWAVES (BT / 64)

// Masks for lazily-permuted simulation. For gate g on logical wire w:
//   gm[g] = XOR mask between the pair's physical indices (column w of Q^-1)
//   gs[g] = selector mask: logical bit w of physical index p = parity(p & gs)
// ms[w] = final selector mask for the Z_w measurement.
struct SimParams {
    unsigned short gs[NGATES];
    unsigned short gm[NGATES];
    unsigned short ms[NQ];
};

__global__ __launch_bounds__(BT) void qsim_kernel(
    const float* __restrict__ x, const float* __restrict__ qw,
    const float* __restrict__ wl, const float* __restrict__ bl,
    float* __restrict__ out, SimParams P)
{
    __shared__ float2 st[NSTATE];     // 128 KB state
    __shared__ float red[NWAVES];

    const int tid = threadIdx.x;
    const int b = blockIdx.x;

    // init |0...0>
    for (int t = tid; t < NSTATE; t += BT) st[t] = make_float2(0.f, 0.f);
    if (tid == 0) st[0] = make_float2(1.f, 0.f);

    for (int g = 0; g < NGATES; ++g) {
        // ---- build the 2x2 gate matrix (uniform across block) ----
        float2 g00, g01, g10, g11;
        if (g < NQ) {
            // RX(x[b][g]): [[c, -i s],[-i s, c]]
            float half = 0.5f * x[b * NQ + g];
            float sh, ch; sincosf(half, &sh, &ch);
            g00 = make_float2(ch, 0.f);
            g01 = make_float2(0.f, -sh);
            g10 = g01;
            g11 = g00;
        } else {
            // Rot(phi,theta,omega) = RZ(omega) RY(theta) RZ(phi), shared across batch
            const float* qp = qw + (g - NQ) * 3;
            float phi = qp[0], th = qp[1], om = qp[2];
            float ct, stt; sincosf(0.5f * th, &stt, &ct);
            float sa, ca; sincosf(0.5f * (phi + om), &sa, &ca);
            float sb, cb; sincosf(0.5f * (phi - om), &sb, &cb);
            g00 = make_float2(ca * ct, -sa * ct);   // e^{-i(phi+om)/2} cos
            g01 = make_float2(-cb * stt, -sb * stt);// -e^{+i(phi-om)/2} sin
            g10 = make_float2(cb * stt, -sb * stt); // e^{-i(phi-om)/2} sin
            g11 = make_float2(ca * ct, sa * ct);    // e^{+i(phi+om)/2} cos
        }

        const unsigned sm = P.gs[g];
        const unsigned m  = P.gm[g];
        const int k = __ffs(m) - 1;           // lowest set bit of xor-mask
        const unsigned lowmask = (1u << k) - 1u;

        __syncthreads();   // previous pass's writes visible

        // enumerate the 8192 pairs: q has bit k == 0, partner q^m has bit k == 1
        for (int t = tid; t < NPAIR; t += BT) {
            unsigned low = ((unsigned)t) & lowmask;
            unsigned q = (((unsigned)t ^ low) << 1) | low;   // insert 0 at bit k
            unsigned sw = __popc(q & sm) & 1u;               // logical bit of q
            unsigned i0 = q ^ (sw ? m : 0u);                 // logical-0 member
            unsigned i1 = i0 ^ m;                            // logical-1 member
            float2 a0 = st[i0];
            float2 a1 = st[i1];
            float2 r0, r1;
            r0.x = g00.x*a0.x - g00.y*a0.y + g01.x*a1.x - g01.y*a1.y;
            r0.y = g00.x*a0.y + g00.y*a0.x + g01.x*a1.y + g01.y*a1.x;
            r1.x = g10.x*a0.x - g10.y*a0.y + g11.x*a1.x - g11.y*a1.y;
            r1.y = g10.x*a0.y + g10.y*a0.x + g11.x*a1.y + g11.y*a1.x;
            st[i0] = r0;
            st[i1] = r1;
        }
    }

    __syncthreads();

    // ---- measurement: logit = sum_p |amp_p|^2 * sum_w sign_w(p)*wl[w] + b ----
    float wlv[NQ];
    #pragma unroll
    for (int w = 0; w < NQ; ++w) wlv[w] = wl[w];

    float acc = 0.f;
    for (int t = tid; t < NSTATE; t += BT) {
        float2 a = st[t];
        float p = fmaf(a.x, a.x, a.y * a.y);
        float ws = 0.f;
        #pragma unroll
        for (int w = 0; w < NQ; ++w) {
            unsigned par = __popc((unsigned)t & (unsigned)P.ms[w]) & 1u;
            ws += par ? -wlv[w] : wlv[w];
        }
        acc = fmaf(p, ws, acc);
    }

    // block reduction
    #pragma unroll
    for (int off = 32; off > 0; off >>= 1) acc += __shfl_down(acc, off, 64);
    int lane = tid & 63, wid = tid >> 6;
    if (lane == 0) red[wid] = acc;
    __syncthreads();
    if (tid == 0) {
        float s = 0.f;
        #pragma unroll
        for (int i = 0; i < NWAVES; ++i) s += red[i];
        out[b] = s + bl[0];
    }
}

extern "C" void kernel_launch(void* const* d_in, const int* in_sizes, int n_in,
                              void* d_out, int out_size, void* d_ws, size_t ws_size,
                              hipStream_t stream) {
    const float* x  = (const float*)d_in[0];   // (B, 14)
    const float* qw = (const float*)d_in[1];   // (3, 14, 3)
    const float* wl = (const float*)d_in[2];   // (1, 14)
    const float* bl = (const float*)d_in[3];   // (1,)
    float* out = (float*)d_out;                // (B, 1)

    const int B = in_sizes[0] / NQ;

    // Build the lazily-permuted gate masks (deterministic, pure CPU).
    // Q: physical -> logical map; s[w] = row w of Q, m[w] = column w of Q^-1.
    SimParams P;
    unsigned s[NQ], m[NQ];
    for (int w = 0; w < NQ; ++w) s[w] = m[w] = 1u << (NQ - 1 - w); // wire 0 = MSB
    int g = 0;
    for (int w = 0; w < NQ; ++w) {  // RX embedding (identity map at this point)
        P.gs[g] = (unsigned short)s[w];
        P.gm[g] = (unsigned short)m[w];
        ++g;
    }
    for (int l = 0; l < NL; ++l) {
        for (int w = 0; w < NQ; ++w) {  // Rot layer l
            P.gs[g] = (unsigned short)s[w];
            P.gm[g] = (unsigned short)m[w];
            ++g;
        }
        int r = (l % (NQ - 1)) + 1;     // PennyLane default ranges: 1,2,3
        for (int w = 0; w < NQ; ++w) {  // CNOT ring: control w, target (w+r)%NQ
            int c = w, t = (w + r) % NQ;
            s[t] ^= s[c];
            m[c] ^= m[t];
        }
    }
    for (int w = 0; w < NQ; ++w) P.ms[w] = (unsigned short)s[w];

    qsim_kernel<<<dim3(B), dim3(BT), 0, stream>>>(x, qw, wl, bl, out, P);
}

// Round 2
// 139.453 us; speedup vs baseline: 1.5617x; 1.5617x over previous
//
#include <hip/hip_runtime.h>

#define NQ 14
#define NSTATE (1 << NQ)       // 16384 amplitudes
#define NQUAD (NSTATE / 4)     // 4096 quads per fused 2-qubit pass
#define NL 3
#define NPASS (NL * 7)         // 7 two-qubit passes per layer, 3 layers
#define BT 1024                // threads per block
#define NWAVES (BT / 64)

// Lazily-permuted simulation (CNOT rings folded into GF(2) index maps).
// For each fused 2-qubit pass: ma/mb = XOR masks pairing the quad members,
// sa/sb = selector masks (logical bit = parity(idx & s)), p1<p2 = pivot bits
// (quad representative has bits p1,p2 == 0). ms[w] = final Z_w selector.
struct PassP {
    unsigned short ma, mb, sa, sb, p1, p2;
};
struct SimParams {
    PassP pass[NPASS];
    unsigned short ms[NQ];
};

struct C2x2 { float2 m[2][2]; };

__device__ __forceinline__ float2 cmul(float2 a, float2 b) {
    return make_float2(a.x * b.x - a.y * b.y, a.x * b.y + a.y * b.x);
}
__device__ __forceinline__ float2 cmac(float2 acc, float2 a, float2 b) {
    acc.x = fmaf(a.x, b.x, fmaf(-a.y, b.y, acc.x));
    acc.y = fmaf(a.x, b.y, fmaf(a.y, b.x, acc.y));
    return acc;
}

// PennyLane Rot(phi,theta,omega) = RZ(omega) RY(theta) RZ(phi)
__device__ __forceinline__ C2x2 rot_gate(const float* qp) {
    float phi = qp[0], th = qp[1], om = qp[2];
    float ct, stt; __sincosf(0.5f * th, &stt, &ct);
    float sa, ca; __sincosf(0.5f * (phi + om), &sa, &ca);
    float sb, cb; __sincosf(0.5f * (phi - om), &sb, &cb);
    C2x2 G;
    G.m[0][0] = make_float2(ca * ct, -sa * ct);    // e^{-i(phi+om)/2} cos
    G.m[0][1] = make_float2(-cb * stt, -sb * stt); // -e^{+i(phi-om)/2} sin
    G.m[1][0] = make_float2(cb * stt, -sb * stt);  // e^{-i(phi-om)/2} sin
    G.m[1][1] = make_float2(ca * ct, sa * ct);     // e^{+i(phi+om)/2} cos
    return G;
}

// G := G * RX(ang)   (RX applied first to the state)
__device__ __forceinline__ C2x2 fuse_rx(C2x2 G, float ang) {
    float sh, ch; __sincosf(0.5f * ang, &sh, &ch);
    float2 c = make_float2(ch, 0.f), is = make_float2(0.f, -sh);
    C2x2 R;
    #pragma unroll
    for (int i = 0; i < 2; ++i) {
        R.m[i][0] = cmac(cmul(G.m[i][0], c), G.m[i][1], is);
        R.m[i][1] = cmac(cmul(G.m[i][1], c), G.m[i][0], is);
    }
    return R;
}

__global__ __launch_bounds__(BT) void qsim_kernel(
    const float* __restrict__ x, const float* __restrict__ qw,
    const float* __restrict__ wl, const float* __restrict__ bl,
    float* __restrict__ out, SimParams P)
{
    __shared__ float2 st[NSTATE];     // 128 KB state
    __shared__ float red[NWAVES];

    const int tid = threadIdx.x;
    const int b = blockIdx.x;

    for (int t = tid; t < NSTATE; t += BT) st[t] = make_float2(0.f, 0.f);
    if (tid == 0) st[0] = make_float2(1.f, 0.f);

    #pragma unroll 1
    for (int ps = 0; ps < NPASS; ++ps) {
        const int L = ps / 7, pr = ps % 7;
        const int wa = 2 * pr, wb = 2 * pr + 1;

        C2x2 Ga = rot_gate(qw + (L * NQ + wa) * 3);
        C2x2 Gb = rot_gate(qw + (L * NQ + wb) * 3);
        if (L == 0) {  // fuse the AngleEmbedding RX into the first Rot layer
            Ga = fuse_rx(Ga, x[b * NQ + wa]);
            Gb = fuse_rx(Gb, x[b * NQ + wb]);
        }
        // 4x4 gate = Ga (x) Gb over logical bits (la, lb)
        float2 G4[4][4];
        #pragma unroll
        for (int ra = 0; ra < 2; ++ra)
            #pragma unroll
            for (int rb = 0; rb < 2; ++rb)
                #pragma unroll
                for (int ca = 0; ca < 2; ++ca)
                    #pragma unroll
                    for (int cb = 0; cb < 2; ++cb)
                        G4[ra * 2 + rb][ca * 2 + cb] = cmul(Ga.m[ra][ca], Gb.m[rb][cb]);

        const unsigned ma = P.pass[ps].ma, mb = P.pass[ps].mb;
        const unsigned sa = P.pass[ps].sa, sb = P.pass[ps].sb;
        const unsigned p1 = P.pass[ps].p1, p2 = P.pass[ps].p2;
        const unsigned lm1 = (1u << p1) - 1u, lm2 = (1u << p2) - 1u;

        __syncthreads();

        for (int t = tid; t < NQUAD; t += BT) {
            unsigned v = (unsigned)t;
            v = ((v & ~lm1) << 1) | (v & lm1);   // insert 0 at bit p1
            v = ((v & ~lm2) << 1) | (v & lm2);   // insert 0 at bit p2 (p2>p1)
            unsigned la = __popc(v & sa) & 1u;
            unsigned lb = __popc(v & sb) & 1u;
            unsigned i00 = v ^ (la ? ma : 0u) ^ (lb ? mb : 0u);
            unsigned i01 = i00 ^ mb;
            unsigned i10 = i00 ^ ma;
            unsigned i11 = i10 ^ mb;
            float2 a0 = st[i00], a1 = st[i01], a2 = st[i10], a3 = st[i11];
            #pragma unroll
            for (int j = 0; j < 4; ++j) {
                float2 r = cmul(G4[j][0], a0);
                r = cmac(r, G4[j][1], a1);
                r = cmac(r, G4[j][2], a2);
                r = cmac(r, G4[j][3], a3);
                if (j == 0) st[i00] = r;
                else if (j == 1) st[i01] = r;
                else if (j == 2) st[i10] = r;
                else st[i11] = r;
            }
        }
    }

    __syncthreads();

    // logit = sum_p |amp_p|^2 * sum_w sign_w(p)*wl[w] + bias
    float wlv[NQ];
    #pragma unroll
    for (int w = 0; w < NQ; ++w) wlv[w] = wl[w];

    float acc = 0.f;
    for (int t = tid; t < NSTATE; t += BT) {
        float2 a = st[t];
        float p = fmaf(a.x, a.x, a.y * a.y);
        float ws = 0.f;
        #pragma unroll
        for (int w = 0; w < NQ; ++w) {
            unsigned par = __popc((unsigned)t & (unsigned)P.ms[w]) & 1u;
            ws += par ? -wlv[w] : wlv[w];
        }
        acc = fmaf(p, ws, acc);
    }

    #pragma unroll
    for (int off = 32; off > 0; off >>= 1) acc += __shfl_down(acc, off, 64);
    int lane = tid & 63, wid = tid >> 6;
    if (lane == 0) red[wid] = acc;
    __syncthreads();
    if (tid == 0) {
        float s = 0.f;
        #pragma unroll
        for (int i = 0; i < NWAVES; ++i) s += red[i];
        out[b] = s + bl[0];
    }
}

extern "C" void kernel_launch(void* const* d_in, const int* in_sizes, int n_in,
                              void* d_out, int out_size, void* d_ws, size_t ws_size,
                              hipStream_t stream) {
    const float* x  = (const float*)d_in[0];   // (B, 14)
    const float* qw = (const float*)d_in[1];   // (3, 14, 3)
    const float* wl = (const float*)d_in[2];   // (1, 14)
    const float* bl = (const float*)d_in[3];   // (1,)
    float* out = (float*)d_out;                // (B, 1)

    const int B = in_sizes[0] / NQ;

    // Lazy-CNOT GF(2) bookkeeping: s[w] = selector row, m[w] = pair column.
    SimParams P;
    unsigned s[NQ], m[NQ];
    for (int w = 0; w < NQ; ++w) s[w] = m[w] = 1u << (NQ - 1 - w); // wire 0 = MSB

    int ps = 0;
    for (int l = 0; l < NL; ++l) {
        for (int pr = 0; pr < 7; ++pr) {   // pair wires (2pr, 2pr+1)
            int wa = 2 * pr, wb = 2 * pr + 1;
            unsigned ma = m[wa], mb = m[wb];
            // GF(2) reduce to pivot bits so projection quad->(p1,p2) is bijective
            unsigned u1 = ma, u2 = mb;
            int q1 = __builtin_ctz(u1);
            if ((u2 >> q1) & 1u) u2 ^= u1;
            int q2 = __builtin_ctz(u2);
            int p1 = q1 < q2 ? q1 : q2, p2 = q1 < q2 ? q2 : q1;
            P.pass[ps].ma = (unsigned short)ma;
            P.pass[ps].mb = (unsigned short)mb;
            P.pass[ps].sa = (unsigned short)s[wa];
            P.pass[ps].sb = (unsigned short)s[wb];
            P.pass[ps].p1 = (unsigned short)p1;
            P.pass[ps].p2 = (unsigned short)p2;
            ++ps;
        }
        int r = (l % (NQ - 1)) + 1;        // PennyLane ranges: 1,2,3
        for (int w = 0; w < NQ; ++w) {     // CNOT ring: control w, target (w+r)%NQ
            int c = w, t = (w + r) % NQ;
            s[t] ^= s[c];
            m[c] ^= m[t];
        }
    }
    for (int w = 0; w < NQ; ++w) P.ms[w] = (unsigned short)s[w];

    qsim_kernel<<<dim3(B), dim3(BT), 0, stream>>>(x, qw, wl, bl, out, P);
}

// Round 3
// 127.316 us; speedup vs baseline: 1.7106x; 1.0953x over previous
//
#include <hip/hip_runtime.h>

#define NQ 14
#define NSTATE (1 << NQ)       // 16384 amplitudes
#define NL 3
#define NPASS (NL * 4)         // 4 fused 4-qubit sweeps per layer
#define BT 1024                // threads per block
#define NWAVES (BT / 64)

// Lazily-permuted simulation: CNOT rings folded into GF(2) index maps.
// Per pass (4 wires fused): R[10] = complement-basis images (tid -> group
// representative, normalized to logical bits = 0), cmb[16] = XOR combos of
// the 4 pair-masks (logical-bit indexed), gidx = gate table indices.
// Duality par(s_i & m_j) = delta_ij guarantees XOR by m_j flips exactly
// logical bit j, so no selector popc is needed in the hot loop.
struct PassP {
    unsigned short R[10];
    unsigned short cmb[16];
    unsigned char gidx[4];
    unsigned char nw;
    unsigned char _pad;
};
struct SimParams {
    PassP pass[NPASS];
    unsigned short ms[NQ];     // final Z_w selector masks
};

struct C2x2 { float2 m[2][2]; };

__device__ __forceinline__ float2 cmul(float2 a, float2 b) {
    return make_float2(a.x * b.x - a.y * b.y, a.x * b.y + a.y * b.x);
}
__device__ __forceinline__ float2 cmac(float2 acc, float2 a, float2 b) {
    acc.x = fmaf(a.x, b.x, fmaf(-a.y, b.y, acc.x));
    acc.y = fmaf(a.x, b.y, fmaf(a.y, b.x, acc.y));
    return acc;
}

// PennyLane Rot(phi,theta,omega) = RZ(omega) RY(theta) RZ(phi)
__device__ __forceinline__ C2x2 rot_gate(const float* qp) {
    float phi = qp[0], th = qp[1], om = qp[2];
    float ct, stt; __sincosf(0.5f * th, &stt, &ct);
    float sa, ca; __sincosf(0.5f * (phi + om), &sa, &ca);
    float sb, cb; __sincosf(0.5f * (phi - om), &sb, &cb);
    C2x2 G;
    G.m[0][0] = make_float2(ca * ct, -sa * ct);    // e^{-i(phi+om)/2} cos
    G.m[0][1] = make_float2(-cb * stt, -sb * stt); // -e^{+i(phi-om)/2} sin
    G.m[1][0] = make_float2(cb * stt, -sb * stt);  // e^{-i(phi-om)/2} sin
    G.m[1][1] = make_float2(ca * ct, sa * ct);     // e^{+i(phi+om)/2} cos
    return G;
}

// G := G * RX(ang)   (RX applied first to the state)
__device__ __forceinline__ C2x2 fuse_rx(C2x2 G, float ang) {
    float sh, ch; __sincosf(0.5f * ang, &sh, &ch);
    float2 c = make_float2(ch, 0.f), is = make_float2(0.f, -sh);
    C2x2 R;
    #pragma unroll
    for (int i = 0; i < 2; ++i) {
        R.m[i][0] = cmac(cmul(G.m[i][0], c), G.m[i][1], is);
        R.m[i][1] = cmac(cmul(G.m[i][1], c), G.m[i][0], is);
    }
    return R;
}

__global__ __launch_bounds__(BT) void qsim_kernel(
    const float* __restrict__ x, const float* __restrict__ qw,
    const float* __restrict__ wl, const float* __restrict__ bl,
    float* __restrict__ out, SimParams P)
{
    __shared__ float2 st[NSTATE];          // 128 KB state
    __shared__ float2 gbuf[NL * NQ * 4];   // 42 precomputed 2x2 gates
    __shared__ float red[NWAVES];

    const int tid = threadIdx.x;
    const int b = blockIdx.x;

    for (int t = tid; t < NSTATE; t += BT) st[t] = make_float2(0.f, 0.f);
    if (tid == 0) st[0] = make_float2(1.f, 0.f);

    // precompute all 2x2 gates once (layer 0 fuses the RX embedding)
    if (tid < NL * NQ) {
        int l = tid / NQ, w = tid % NQ;
        C2x2 G = rot_gate(qw + tid * 3);
        if (l == 0) G = fuse_rx(G, x[b * NQ + w]);
        gbuf[tid * 4 + 0] = G.m[0][0];
        gbuf[tid * 4 + 1] = G.m[0][1];
        gbuf[tid * 4 + 2] = G.m[1][0];
        gbuf[tid * 4 + 3] = G.m[1][1];
    }

    #pragma unroll 1
    for (int ps = 0; ps < NPASS; ++ps) {
        __syncthreads();   // previous pass's writes (or init) visible

        // group representative: GF(2)-linear in tid, logical bits all 0
        unsigned r = 0;
        #pragma unroll
        for (int j = 0; j < 10; ++j)
            r ^= ((tid >> j) & 1) ? (unsigned)P.pass[ps].R[j] : 0u;
        const unsigned rb = r << 3;          // byte offset

        unsigned c8[16];
        #pragma unroll
        for (int i = 0; i < 16; ++i)
            c8[i] = ((unsigned)P.pass[ps].cmb[i]) << 3;

        char* sb = (char*)st;
        float2 a[16];
        #pragma unroll
        for (int i = 0; i < 16; ++i)
            a[i] = *(const float2*)(sb + (rb ^ c8[i]));

        // staged 2x2 applications; a[] is indexed by logical bits
        const int nw = P.pass[ps].nw;
        #pragma unroll
        for (int q = 0; q < 4; ++q) {
            if (q < nw) {    // wave-uniform branch
                const int gi = (int)P.pass[ps].gidx[q] * 4;
                float2 g00 = gbuf[gi + 0], g01 = gbuf[gi + 1];
                float2 g10 = gbuf[gi + 2], g11 = gbuf[gi + 3];
                #pragma unroll
                for (int i = 0; i < 16; ++i) {
                    if (!((i >> q) & 1)) {
                        const int i1 = i | (1 << q);
                        float2 a0 = a[i], a1 = a[i1];
                        float2 n0 = cmac(cmul(g00, a0), g01, a1);
                        float2 n1 = cmac(cmul(g10, a0), g11, a1);
                        a[i] = n0; a[i1] = n1;
                    }
                }
            }
        }

        #pragma unroll
        for (int i = 0; i < 16; ++i)
            *(float2*)(sb + (rb ^ c8[i])) = a[i];
    }

    __syncthreads();

    // logit = sum_p |amp_p|^2 * sum_w sign_w(p)*wl[w] + bias
    float wlv[NQ];
    #pragma unroll
    for (int w = 0; w < NQ; ++w) wlv[w] = wl[w];

    float acc = 0.f;
    for (int t = tid; t < NSTATE; t += BT) {
        float2 a = st[t];
        float p = fmaf(a.x, a.x, a.y * a.y);
        float ws = 0.f;
        #pragma unroll
        for (int w = 0; w < NQ; ++w) {
            unsigned par = __popc((unsigned)t & (unsigned)P.ms[w]) & 1u;
            ws += par ? -wlv[w] : wlv[w];
        }
        acc = fmaf(p, ws, acc);
    }

    #pragma unroll
    for (int off = 32; off > 0; off >>= 1) acc += __shfl_down(acc, off, 64);
    int lane = tid & 63, wid = tid >> 6;
    if (lane == 0) red[wid] = acc;
    __syncthreads();
    if (tid == 0) {
        float s = 0.f;
        #pragma unroll
        for (int i = 0; i < NWAVES; ++i) s += red[i];
        out[b] = s + bl[0];
    }
}

// ---- host-side GF(2) reduced-basis helper ----
struct GF2Basis {
    unsigned piv[NQ];
    GF2Basis() { for (int i = 0; i < NQ; ++i) piv[i] = 0; }
    bool insert(unsigned v) {            // true iff rank increased
        for (int bb = NQ - 1; bb >= 0; --bb) {
            if (!((v >> bb) & 1)) continue;
            if (piv[bb]) v ^= piv[bb];
            else { piv[bb] = v; return true; }
        }
        return false;
    }
};

static inline int par16(unsigned v) { return __builtin_parity(v); }

extern "C" void kernel_launch(void* const* d_in, const int* in_sizes, int n_in,
                              void* d_out, int out_size, void* d_ws, size_t ws_size,
                              hipStream_t stream) {
    const float* x  = (const float*)d_in[0];   // (B, 14)
    const float* qw = (const float*)d_in[1];   // (3, 14, 3)
    const float* wl = (const float*)d_in[2];   // (1, 14)
    const float* bl = (const float*)d_in[3];   // (1,)
    float* out = (float*)d_out;                // (B, 1)

    const int B = in_sizes[0] / NQ;

    // Lazy-CNOT GF(2) bookkeeping: s[w] = selector row of Q, m[w] = column of
    // Q^-1. Invariant: par(s_i & m_j) = delta_ij.
    SimParams P;
    unsigned s[NQ], m[NQ];
    for (int w = 0; w < NQ; ++w) s[w] = m[w] = 1u << (NQ - 1 - w); // wire 0 = MSB

    int ps = 0;
    for (int l = 0; l < NL; ++l) {
        for (int g0 = 0; g0 < NQ; g0 += 4) {
            int nw = (NQ - g0) < 4 ? (NQ - g0) : 4;
            unsigned mm[4], ss[4];
            GF2Basis gf;
            for (int i = 0; i < nw; ++i) { mm[i] = m[g0 + i]; ss[i] = s[g0 + i]; gf.insert(mm[i]); }
            // pad to 4 independent masks; normalize pads so they don't flip
            // the real wires' logical bits
            for (int i = nw; i < 4; ++i) {
                unsigned cand = 0;
                for (int t = 0; t < NQ; ++t)
                    if (gf.insert(1u << t)) { cand = 1u << t; break; }
                for (int j = 0; j < nw; ++j)
                    if (par16(cand & ss[j])) cand ^= mm[j];
                mm[i] = cand; ss[i] = 0;
            }
            // complement basis (10 vecs), normalized to zero logical bits
            int nR = 0;
            for (int t = 0; t < NQ && nR < 10; ++t) {
                if (gf.insert(1u << t)) {
                    unsigned rv = 1u << t;
                    for (int j = 0; j < nw; ++j)
                        if (par16(rv & ss[j])) rv ^= mm[j];
                    P.pass[ps].R[nR++] = (unsigned short)rv;
                }
            }
            for (int idx = 0; idx < 16; ++idx) {
                unsigned c = 0;
                for (int q = 0; q < 4; ++q) if ((idx >> q) & 1) c ^= mm[q];
                P.pass[ps].cmb[idx] = (unsigned short)c;
            }
            for (int q = 0; q < 4; ++q)
                P.pass[ps].gidx[q] = (unsigned char)(q < nw ? (l * NQ + g0 + q) : 0);
            P.pass[ps].nw = (unsigned char)nw;
            P.pass[ps]._pad = 0;
            ++ps;
        }
        int r = (l % (NQ - 1)) + 1;        // PennyLane ranges: 1,2,3
        for (int w = 0; w < NQ; ++w) {     // CNOT ring: control w, target (w+r)%NQ
            int c = w, t = (w + r) % NQ;
            s[t] ^= s[c];
            m[c] ^= m[t];
        }
    }
    for (int w = 0; w < NQ; ++w) P.ms[w] = (unsigned short)s[w];

    qsim_kernel<<<dim3(B), dim3(BT), 0, stream>>>(x, qw, wl, bl, out, P);
}

// Round 4
// 125.434 us; speedup vs baseline: 1.7363x; 1.0150x over previous
//
#include <hip/hip_runtime.h>

#define NQ 14
#define NSTATE (1 << NQ)       // 16384 amplitudes
#define NL 3
#define NPASS (NL * 4)         // 4 fused 4-qubit sweeps per layer
#define BT 1024                // threads per block
#define NWAVES (BT / 64)

// Lazily-permuted simulation: CNOT rings folded into GF(2) index maps.
// Per pass (4 wires fused): R[10] = complement-basis images (tid -> group
// representative, normalized to logical bits = 0), cmb[16] = XOR combos of
// the 4 pair-masks (logical-bit indexed), gidx = gate table indices.
// Duality par(s_i & m_j) = delta_ij guarantees XOR by m_j flips exactly
// logical bit j, so no selector popc is needed in the hot loop.
// R is bank-normalized: R[0..3] have independent low-4-bit projections,
// R[4..9] have zero low-4 bits -> each wave's 64 lanes spread 4-per-bank-pair
// on every ds_read/write_b64 (the b64 floor; conflict-free).
struct PassP {
    unsigned short R[10];
    unsigned short cmb[16];
    unsigned char gidx[4];
    unsigned char nw;
    unsigned char _pad;
};
struct SimParams {
    PassP pass[NPASS];
    unsigned short ms[NQ];     // final Z_w selector masks
};

struct C2x2 { float2 m[2][2]; };

__device__ __forceinline__ float2 cmul(float2 a, float2 b) {
    return make_float2(a.x * b.x - a.y * b.y, a.x * b.y + a.y * b.x);
}
__device__ __forceinline__ float2 cmac(float2 acc, float2 a, float2 b) {
    acc.x = fmaf(a.x, b.x, fmaf(-a.y, b.y, acc.x));
    acc.y = fmaf(a.x, b.y, fmaf(a.y, b.x, acc.y));
    return acc;
}

// PennyLane Rot(phi,theta,omega) = RZ(omega) RY(theta) RZ(phi)
__device__ __forceinline__ C2x2 rot_gate(const float* qp) {
    float phi = qp[0], th = qp[1], om = qp[2];
    float ct, stt; __sincosf(0.5f * th, &stt, &ct);
    float sa, ca; __sincosf(0.5f * (phi + om), &sa, &ca);
    float sb, cb; __sincosf(0.5f * (phi - om), &sb, &cb);
    C2x2 G;
    G.m[0][0] = make_float2(ca * ct, -sa * ct);    // e^{-i(phi+om)/2} cos
    G.m[0][1] = make_float2(-cb * stt, -sb * stt); // -e^{+i(phi-om)/2} sin
    G.m[1][0] = make_float2(cb * stt, -sb * stt);  // e^{-i(phi-om)/2} sin
    G.m[1][1] = make_float2(ca * ct, sa * ct);     // e^{+i(phi+om)/2} cos
    return G;
}

// G := G * RX(ang)   (RX applied first to the state)
__device__ __forceinline__ C2x2 fuse_rx(C2x2 G, float ang) {
    float sh, ch; __sincosf(0.5f * ang, &sh, &ch);
    float2 c = make_float2(ch, 0.f), is = make_float2(0.f, -sh);
    C2x2 R;
    #pragma unroll
    for (int i = 0; i < 2; ++i) {
        R.m[i][0] = cmac(cmul(G.m[i][0], c), G.m[i][1], is);
        R.m[i][1] = cmac(cmul(G.m[i][1], c), G.m[i][0], is);
    }
    return R;
}

__global__ __launch_bounds__(BT) void qsim_kernel(
    const float* __restrict__ x, const float* __restrict__ qw,
    const float* __restrict__ wl, const float* __restrict__ bl,
    float* __restrict__ out, SimParams P)
{
    __shared__ float2 st[NSTATE];          // 128 KB state
    __shared__ float2 gbuf[NL * NQ * 4];   // 42 precomputed 2x2 gates
    __shared__ float red[NWAVES];

    const int tid = threadIdx.x;
    const int b = blockIdx.x;

    for (int t = tid; t < NSTATE; t += BT) st[t] = make_float2(0.f, 0.f);
    if (tid == 0) st[0] = make_float2(1.f, 0.f);

    // precompute all 2x2 gates once (layer 0 fuses the RX embedding)
    if (tid < NL * NQ) {
        int l = tid / NQ, w = tid % NQ;
        C2x2 G = rot_gate(qw + tid * 3);
        if (l == 0) G = fuse_rx(G, x[b * NQ + w]);
        gbuf[tid * 4 + 0] = G.m[0][0];
        gbuf[tid * 4 + 1] = G.m[0][1];
        gbuf[tid * 4 + 2] = G.m[1][0];
        gbuf[tid * 4 + 3] = G.m[1][1];
    }

    #pragma unroll 1
    for (int ps = 0; ps < NPASS; ++ps) {
        __syncthreads();   // previous pass's writes (or init) visible

        // group representative: GF(2)-linear in tid, logical bits all 0
        unsigned r = 0;
        #pragma unroll
        for (int j = 0; j < 10; ++j)
            r ^= ((tid >> j) & 1) ? (unsigned)P.pass[ps].R[j] : 0u;
        const unsigned rb = r << 3;          // byte offset

        unsigned c8[16];
        #pragma unroll
        for (int i = 0; i < 16; ++i)
            c8[i] = ((unsigned)P.pass[ps].cmb[i]) << 3;

        char* sb = (char*)st;
        float2 a[16];
        #pragma unroll
        for (int i = 0; i < 16; ++i)
            a[i] = *(const float2*)(sb + (rb ^ c8[i]));

        // staged 2x2 applications; a[] is indexed by logical bits
        const int nw = P.pass[ps].nw;
        #pragma unroll
        for (int q = 0; q < 4; ++q) {
            if (q < nw) {    // wave-uniform branch
                const int gi = (int)P.pass[ps].gidx[q] * 4;
                float2 g00 = gbuf[gi + 0], g01 = gbuf[gi + 1];
                float2 g10 = gbuf[gi + 2], g11 = gbuf[gi + 3];
                #pragma unroll
                for (int i = 0; i < 16; ++i) {
                    if (!((i >> q) & 1)) {
                        const int i1 = i | (1 << q);
                        float2 a0 = a[i], a1 = a[i1];
                        float2 n0 = cmac(cmul(g00, a0), g01, a1);
                        float2 n1 = cmac(cmul(g10, a0), g11, a1);
                        a[i] = n0; a[i1] = n1;
                    }
                }
            }
        }

        #pragma unroll
        for (int i = 0; i < 16; ++i)
            *(float2*)(sb + (rb ^ c8[i])) = a[i];
    }

    __syncthreads();

    // ---- measurement: logit = sum_p |amp_p|^2 * ws(p) + bias,
    // ws(p) = sum_w wl[w]*(1-2*par(p & ms[w])).  p = k*BT + tid, so split
    // the parity: thread-part (tid & low10) gives a signed weight once;
    // k-part (4 bits, wave-uniform) selects sign into 16 accumulators.
    float A[16];
    #pragma unroll
    for (int k = 0; k < 16; ++k) A[k] = 0.f;
    #pragma unroll
    for (int w = 0; w < NQ; ++w) {
        const unsigned msw = (unsigned)P.ms[w];
        float v = wl[w];
        unsigned s0 = __popc((unsigned)tid & (msw & 1023u)) & 1u;
        float vs = s0 ? -v : v;
        const unsigned hk = msw >> 10;      // wave-uniform 4-bit pattern
        #pragma unroll
        for (int k = 0; k < 16; ++k) {
            bool neg = (__popc((unsigned)k & hk) & 1) != 0;
            A[k] += neg ? -vs : vs;
        }
    }

    float acc = 0.f;
    #pragma unroll
    for (int k = 0; k < 16; ++k) {
        float2 a = st[k * BT + tid];
        acc = fmaf(fmaf(a.x, a.x, a.y * a.y), A[k], acc);
    }

    #pragma unroll
    for (int off = 32; off > 0; off >>= 1) acc += __shfl_down(acc, off, 64);
    int lane = tid & 63, wid = tid >> 6;
    if (lane == 0) red[wid] = acc;
    __syncthreads();
    if (tid == 0) {
        float s = 0.f;
        #pragma unroll
        for (int i = 0; i < NWAVES; ++i) s += red[i];
        out[b] = s + bl[0];
    }
}

// ---- host-side GF(2) reduced-basis helper ----
struct GF2Basis {
    unsigned piv[NQ];
    GF2Basis() { for (int i = 0; i < NQ; ++i) piv[i] = 0; }
    bool insert(unsigned v) {            // true iff rank increased
        for (int bb = NQ - 1; bb >= 0; --bb) {
            if (!((v >> bb) & 1)) continue;
            if (piv[bb]) v ^= piv[bb];
            else { piv[bb] = v; return true; }
        }
        return false;
    }
};

static inline int par16(unsigned v) { return __builtin_parity(v); }

extern "C" void kernel_launch(void* const* d_in, const int* in_sizes, int n_in,
                              void* d_out, int out_size, void* d_ws, size_t ws_size,
                              hipStream_t stream) {
    const float* x  = (const float*)d_in[0];   // (B, 14)
    const float* qw = (const float*)d_in[1];   // (3, 14, 3)
    const float* wl = (const float*)d_in[2];   // (1, 14)
    const float* bl = (const float*)d_in[3];   // (1,)
    float* out = (float*)d_out;                // (B, 1)

    const int B = in_sizes[0] / NQ;

    // Lazy-CNOT GF(2) bookkeeping: s[w] = selector row of Q, m[w] = column of
    // Q^-1. Invariant: par(s_i & m_j) = delta_ij.
    SimParams P;
    unsigned s[NQ], m[NQ];
    for (int w = 0; w < NQ; ++w) s[w] = m[w] = 1u << (NQ - 1 - w); // wire 0 = MSB

    int ps = 0;
    for (int l = 0; l < NL; ++l) {
        for (int g0 = 0; g0 < NQ; g0 += 4) {
            int nw = (NQ - g0) < 4 ? (NQ - g0) : 4;
            unsigned mm[4], ss[4];
            GF2Basis gf;
            for (int i = 0; i < nw; ++i) { mm[i] = m[g0 + i]; ss[i] = s[g0 + i]; gf.insert(mm[i]); }
            // pad to 4 independent masks; normalize pads so they don't flip
            // the real wires' logical bits
            for (int i = nw; i < 4; ++i) {
                unsigned cand = 0;
                for (int t = 0; t < NQ; ++t)
                    if (gf.insert(1u << t)) { cand = 1u << t; break; }
                for (int j = 0; j < nw; ++j)
                    if (par16(cand & ss[j])) cand ^= mm[j];
                mm[i] = cand; ss[i] = 0;
            }
            // complement basis (10 vecs), normalized to zero logical bits
            unsigned rv[10]; int nR = 0;
            for (int t = 0; t < NQ && nR < 10; ++t) {
                if (gf.insert(1u << t)) {
                    unsigned v = 1u << t;
                    for (int j = 0; j < nw; ++j)
                        if (par16(v & ss[j])) v ^= mm[j];
                    rv[nR++] = v;
                }
            }
            // bank-aware re-basis: positions 0..3 get vectors with independent
            // low-4-bit projections (pivots), the rest have zero low-4 bits.
            // Then within a wave (tid bits 0..5) the 64 lanes spread exactly
            // 4-per-bank-pair on every b64 LDS access.
            unsigned piv4[4] = {0, 0, 0, 0};
            unsigned chosen[4]; int nch = 0;
            unsigned lo[10]; int nlo = 0;
            for (int i = 0; i < nR; ++i) {
                unsigned w2 = rv[i];
                for (int bb = 0; bb < 4; ++bb)
                    if (((w2 >> bb) & 1) && piv4[bb]) w2 ^= piv4[bb];
                unsigned l4 = w2 & 0xFu;
                if (l4 && nch < 4) {
                    piv4[__builtin_ctz(l4)] = w2;
                    chosen[nch++] = w2;
                } else {
                    lo[nlo++] = w2;
                }
            }
            int kk = 0;
            for (int i = 0; i < nch; ++i) P.pass[ps].R[kk++] = (unsigned short)chosen[i];
            for (int i = 0; i < nlo; ++i) P.pass[ps].R[kk++] = (unsigned short)lo[i];

            for (int idx = 0; idx < 16; ++idx) {
                unsigned c = 0;
                for (int q = 0; q < 4; ++q) if ((idx >> q) & 1) c ^= mm[q];
                P.pass[ps].cmb[idx] = (unsigned short)c;
            }
            for (int q = 0; q < 4; ++q)
                P.pass[ps].gidx[q] = (unsigned char)(q < nw ? (l * NQ + g0 + q) : 0);
            P.pass[ps].nw = (unsigned char)nw;
            P.pass[ps]._pad = 0;
            ++ps;
        }
        int r = (l % (NQ - 1)) + 1;        // PennyLane ranges: 1,2,3
        for (int w = 0; w < NQ; ++w) {     // CNOT ring: control w, target (w+r)%NQ
            int c = w, t = (w + r) % NQ;
            s[t] ^= s[c];
            m[c] ^= m[t];
        }
    }
    for (int w = 0; w < NQ; ++w) P.ms[w] = (unsigned short)s[w];

    qsim_kernel<<<dim3(B), dim3(BT), 0, stream>>>(x, qw, wl, bl, out, P);
}

// Round 5
// 114.634 us; speedup vs baseline: 1.8999x; 1.0942x over previous
//
#include <hip/hip_runtime.h>

#define NQ 14
#define NSTATE (1 << NQ)       // 16384 amplitudes
#define NL 3
#define NPASS (NL * 4)         // 4 fused 4-qubit sweeps per layer
#define BT 1024                // threads per block
#define NWAVES (BT / 64)

// Lazily-permuted simulation: CNOT rings folded into GF(2) index maps, and a
// global GF(2)-linear LDS layout sigma (amp p stored at address sigma(p)).
// sigma is chosen host-side so that EVERY pass's representative space
// projects with full rank 4 onto the bank-pair bits (addr mod 16) -> each
// ds_read/write_b64 spreads 4 lanes/bank-pair (2 per 32-lane phase), the
// data-volume floor. Per pass: R[10] = complement-basis images (tid ->
// group representative; R[0..3] are bank pivots), cmb[16] = XOR combos of
// the 4 pair-masks (logical-bit indexed), gidx = gate table indices.
struct PassP {
    unsigned short R[10];
    unsigned short cmb[16];
    unsigned char gidx[4];
    unsigned char nw;
    unsigned char _pad;
};
struct SimParams {
    PassP pass[NPASS];
    unsigned short ms[NQ];     // final Z_w selector masks (address space)
};

struct C2x2 { float2 m[2][2]; };

__device__ __forceinline__ float2 cmul(float2 a, float2 b) {
    return make_float2(a.x * b.x - a.y * b.y, a.x * b.y + a.y * b.x);
}
__device__ __forceinline__ float2 cmac(float2 acc, float2 a, float2 b) {
    acc.x = fmaf(a.x, b.x, fmaf(-a.y, b.y, acc.x));
    acc.y = fmaf(a.x, b.y, fmaf(a.y, b.x, acc.y));
    return acc;
}

// PennyLane Rot(phi,theta,omega) = RZ(omega) RY(theta) RZ(phi)
__device__ __forceinline__ C2x2 rot_gate(const float* qp) {
    float phi = qp[0], th = qp[1], om = qp[2];
    float ct, stt; __sincosf(0.5f * th, &stt, &ct);
    float sa, ca; __sincosf(0.5f * (phi + om), &sa, &ca);
    float sb, cb; __sincosf(0.5f * (phi - om), &sb, &cb);
    C2x2 G;
    G.m[0][0] = make_float2(ca * ct, -sa * ct);    // e^{-i(phi+om)/2} cos
    G.m[0][1] = make_float2(-cb * stt, -sb * stt); // -e^{+i(phi-om)/2} sin
    G.m[1][0] = make_float2(cb * stt, -sb * stt);  // e^{-i(phi-om)/2} sin
    G.m[1][1] = make_float2(ca * ct, sa * ct);     // e^{+i(phi+om)/2} cos
    return G;
}

// G := G * RX(ang)   (RX applied first to the state)
__device__ __forceinline__ C2x2 fuse_rx(C2x2 G, float ang) {
    float sh, ch; __sincosf(0.5f * ang, &sh, &ch);
    float2 c = make_float2(ch, 0.f), is = make_float2(0.f, -sh);
    C2x2 R;
    #pragma unroll
    for (int i = 0; i < 2; ++i) {
        R.m[i][0] = cmac(cmul(G.m[i][0], c), G.m[i][1], is);
        R.m[i][1] = cmac(cmul(G.m[i][1], c), G.m[i][0], is);
    }
    return R;
}

__global__ __launch_bounds__(BT) void qsim_kernel(
    const float* __restrict__ x, const float* __restrict__ qw,
    const float* __restrict__ wl, const float* __restrict__ bl,
    float* __restrict__ out, SimParams P)
{
    __shared__ float2 st[NSTATE];          // 128 KB state
    __shared__ float2 gbuf[NL * NQ * 4];   // 42 precomputed 2x2 gates
    __shared__ float red[NWAVES];

    const int tid = threadIdx.x;
    const int b = blockIdx.x;

    for (int t = tid; t < NSTATE; t += BT) st[t] = make_float2(0.f, 0.f);
    if (tid == 0) st[0] = make_float2(1.f, 0.f);   // sigma(0) = 0

    // precompute all 2x2 gates once (layer 0 fuses the RX embedding)
    if (tid < NL * NQ) {
        int l = tid / NQ, w = tid % NQ;
        C2x2 G = rot_gate(qw + tid * 3);
        if (l == 0) G = fuse_rx(G, x[b * NQ + w]);
        gbuf[tid * 4 + 0] = G.m[0][0];
        gbuf[tid * 4 + 1] = G.m[0][1];
        gbuf[tid * 4 + 2] = G.m[1][0];
        gbuf[tid * 4 + 3] = G.m[1][1];
    }

    #pragma unroll 1
    for (int ps = 0; ps < NPASS; ++ps) {
        __syncthreads();   // previous pass's writes (or init) visible

        // group representative: GF(2)-linear in tid, logical bits all 0
        unsigned r = 0;
        #pragma unroll
        for (int j = 0; j < 10; ++j)
            r ^= ((tid >> j) & 1) ? (unsigned)P.pass[ps].R[j] : 0u;
        const unsigned rb = r << 3;          // byte offset

        unsigned c8[16];
        #pragma unroll
        for (int i = 0; i < 16; ++i)
            c8[i] = ((unsigned)P.pass[ps].cmb[i]) << 3;

        char* sb = (char*)st;
        float2 a[16];
        #pragma unroll
        for (int i = 0; i < 16; ++i)
            a[i] = *(const float2*)(sb + (rb ^ c8[i]));

        // staged 2x2 applications; a[] is indexed by logical bits
        const int nw = P.pass[ps].nw;
        #pragma unroll
        for (int q = 0; q < 4; ++q) {
            if (q < nw) {    // wave-uniform branch
                const int gi = (int)P.pass[ps].gidx[q] * 4;
                float2 g00 = gbuf[gi + 0], g01 = gbuf[gi + 1];
                float2 g10 = gbuf[gi + 2], g11 = gbuf[gi + 3];
                #pragma unroll
                for (int i = 0; i < 16; ++i) {
                    if (!((i >> q) & 1)) {
                        const int i1 = i | (1 << q);
                        float2 a0 = a[i], a1 = a[i1];
                        float2 n0 = cmac(cmul(g00, a0), g01, a1);
                        float2 n1 = cmac(cmul(g10, a0), g11, a1);
                        a[i] = n0; a[i1] = n1;
                    }
                }
            }
        }

        #pragma unroll
        for (int i = 0; i < 16; ++i)
            *(float2*)(sb + (rb ^ c8[i])) = a[i];
    }

    __syncthreads();

    // ---- measurement: logit = sum_p |amp_p|^2 * ws(p) + bias, with masks
    // already transformed to address space. addr = k*BT + tid: thread-part
    // parity gives a signed weight once; k-part (4 bits, wave-uniform)
    // selects sign into 16 accumulators.
    float A[16];
    #pragma unroll
    for (int k = 0; k < 16; ++k) A[k] = 0.f;
    #pragma unroll
    for (int w = 0; w < NQ; ++w) {
        const unsigned msw = (unsigned)P.ms[w];
        float v = wl[w];
        unsigned s0 = __popc((unsigned)tid & (msw & 1023u)) & 1u;
        float vs = s0 ? -v : v;
        const unsigned hk = msw >> 10;      // wave-uniform 4-bit pattern
        #pragma unroll
        for (int k = 0; k < 16; ++k) {
            bool neg = (__popc((unsigned)k & hk) & 1) != 0;
            A[k] += neg ? -vs : vs;
        }
    }

    float acc = 0.f;
    #pragma unroll
    for (int k = 0; k < 16; ++k) {
        float2 a = st[k * BT + tid];
        acc = fmaf(fmaf(a.x, a.x, a.y * a.y), A[k], acc);
    }

    #pragma unroll
    for (int off = 32; off > 0; off >>= 1) acc += __shfl_down(acc, off, 64);
    int lane = tid & 63, wid = tid >> 6;
    if (lane == 0) red[wid] = acc;
    __syncthreads();
    if (tid == 0) {
        float s = 0.f;
        #pragma unroll
        for (int i = 0; i < NWAVES; ++i) s += red[i];
        out[b] = s + bl[0];
    }
}

// ---- host-side GF(2) helpers ----
struct GF2Basis {
    unsigned piv[NQ];
    GF2Basis() { for (int i = 0; i < NQ; ++i) piv[i] = 0; }
    bool insert(unsigned v) {            // true iff rank increased
        for (int bb = NQ - 1; bb >= 0; --bb) {
            if (!((v >> bb) & 1)) continue;
            if (piv[bb]) v ^= piv[bb];
            else { piv[bb] = v; return true; }
        }
        return false;
    }
};

static inline int par16(unsigned v) { return __builtin_parity(v); }
static inline unsigned lcg_next(unsigned& s) { s = s * 1664525u + 1013904223u; return s >> 8; }

static unsigned gf_apply(const unsigned* C, unsigned v) {
    unsigned r = 0;
    while (v) { int j = __builtin_ctz(v); v &= v - 1; r ^= C[j]; }
    return r;
}

// C = columns of sigma; on success Ci = columns of sigma^{-1}
static bool gf_invert(const unsigned* C, unsigned* Ci) {
    unsigned rows[NQ], irows[NQ];
    for (int i = 0; i < NQ; ++i) {
        unsigned r = 0;
        for (int j = 0; j < NQ; ++j) r |= ((C[j] >> i) & 1u) << j;
        rows[i] = r; irows[i] = 1u << i;
    }
    for (int c = 0; c < NQ; ++c) {
        int p = -1;
        for (int r = c; r < NQ; ++r) if ((rows[r] >> c) & 1u) { p = r; break; }
        if (p < 0) return false;
        unsigned t = rows[p]; rows[p] = rows[c]; rows[c] = t;
        t = irows[p]; irows[p] = irows[c]; irows[c] = t;
        for (int r = 0; r < NQ; ++r)
            if (r != c && ((rows[r] >> c) & 1u)) { rows[r] ^= rows[c]; irows[r] ^= irows[c]; }
    }
    for (int j = 0; j < NQ; ++j) {
        unsigned col = 0;
        for (int i = 0; i < NQ; ++i) col |= ((irows[i] >> j) & 1u) << i;
        Ci[j] = col;
    }
    return true;
}

extern "C" void kernel_launch(void* const* d_in, const int* in_sizes, int n_in,
                              void* d_out, int out_size, void* d_ws, size_t ws_size,
                              hipStream_t stream) {
    const float* x  = (const float*)d_in[0];   // (B, 14)
    const float* qw = (const float*)d_in[1];   // (3, 14, 3)
    const float* wl = (const float*)d_in[2];   // (1, 14)
    const float* bl = (const float*)d_in[3];   // (1,)
    float* out = (float*)d_out;                // (B, 1)

    const int B = in_sizes[0] / NQ;

    // ---- build passes in INDEX space (lazy-CNOT GF(2) bookkeeping) ----
    // s[w] = selector row of Q, m[w] = column of Q^-1; par(s_i & m_j)=delta_ij.
    struct Raw { unsigned mm[4], rv[10], cmb[16]; unsigned char gidx[4], nw; } raw[NPASS];
    unsigned s[NQ], m[NQ], msIdx[NQ];
    for (int w = 0; w < NQ; ++w) s[w] = m[w] = 1u << (NQ - 1 - w); // wire 0 = MSB

    int ps = 0;
    for (int l = 0; l < NL; ++l) {
        for (int g0 = 0; g0 < NQ; g0 += 4) {
            int nw = (NQ - g0) < 4 ? (NQ - g0) : 4;
            unsigned mm[4], ss[4];
            GF2Basis gf;
            for (int i = 0; i < nw; ++i) { mm[i] = m[g0 + i]; ss[i] = s[g0 + i]; gf.insert(mm[i]); }
            // pad to 4 independent masks; normalize pads so they don't flip
            // the real wires' logical bits
            for (int i = nw; i < 4; ++i) {
                unsigned cand = 0;
                for (int t = 0; t < NQ; ++t)
                    if (gf.insert(1u << t)) { cand = 1u << t; break; }
                for (int j = 0; j < nw; ++j)
                    if (par16(cand & ss[j])) cand ^= mm[j];
                mm[i] = cand; ss[i] = 0;
            }
            // complement basis (10 vecs), normalized to zero logical bits
            int nR = 0;
            for (int t = 0; t < NQ && nR < 10; ++t) {
                if (gf.insert(1u << t)) {
                    unsigned v = 1u << t;
                    for (int j = 0; j < nw; ++j)
                        if (par16(v & ss[j])) v ^= mm[j];
                    raw[ps].rv[nR++] = v;
                }
            }
            for (int idx = 0; idx < 16; ++idx) {
                unsigned c = 0;
                for (int q = 0; q < 4; ++q) if ((idx >> q) & 1) c ^= mm[q];
                raw[ps].cmb[idx] = c;
                if (idx < 4) raw[ps].mm[idx] = mm[idx];
            }
            for (int q = 0; q < 4; ++q)
                raw[ps].gidx[q] = (unsigned char)(q < nw ? (l * NQ + g0 + q) : 0);
            raw[ps].nw = (unsigned char)nw;
            ++ps;
        }
        int r = (l % (NQ - 1)) + 1;        // PennyLane ranges: 1,2,3
        for (int w = 0; w < NQ; ++w) {     // CNOT ring: control w, target (w+r)%NQ
            int c = w, t = (w + r) % NQ;
            s[t] ^= s[c];
            m[c] ^= m[t];
        }
    }
    for (int w = 0; w < NQ; ++w) msIdx[w] = s[w];

    // ---- choose layout sigma: every pass's rep space must project with
    // rank 4 onto the bank-pair bits (addr mod 16) ----
    unsigned Cm[NQ], Ci[NQ];
    unsigned seed = 0x9E3779B9u;
    bool found = false;
    for (int tries = 0; tries < 5000 && !found; ++tries) {
        for (int j = 0; j < NQ; ++j) Cm[j] = lcg_next(seed) & (NSTATE - 1);
        if (!gf_invert(Cm, Ci)) continue;
        found = true;
        for (int p = 0; p < NPASS && found; ++p) {
            unsigned piv[4] = {0, 0, 0, 0}; int np = 0;
            for (int i = 0; i < 10; ++i) {
                unsigned w2 = gf_apply(Cm, raw[p].rv[i]);
                for (int bb = 0; bb < 4; ++bb)
                    if (((w2 >> bb) & 1u) && piv[bb]) w2 ^= piv[bb];
                if ((w2 & 15u) && np < 4) { piv[__builtin_ctz(w2 & 15u)] = w2; ++np; }
            }
            if (np < 4) found = false;
        }
    }
    if (!found) {  // fallback: identity layout (correct, just slower)
        for (int j = 0; j < NQ; ++j) Cm[j] = 1u << j;
        gf_invert(Cm, Ci);
    }

    // ---- emit device params in ADDRESS space ----
    SimParams P;
    for (int p = 0; p < NPASS; ++p) {
        unsigned u[10];
        for (int i = 0; i < 10; ++i) u[i] = gf_apply(Cm, raw[p].rv[i]);
        // order: 4 bank-pivot vectors first (they cover lane bits 0..3)
        unsigned piv[4] = {0, 0, 0, 0};
        int ord[10], np = 0, rest[10], nrest = 0;
        for (int i = 0; i < 10; ++i) {
            unsigned w2 = u[i];
            for (int bb = 0; bb < 4; ++bb)
                if (((w2 >> bb) & 1u) && piv[bb]) w2 ^= piv[bb];
            if ((w2 & 15u) && np < 4) { piv[__builtin_ctz(w2 & 15u)] = w2; ord[np++] = i; }
            else rest[nrest++] = i;
        }
        int kk = 0;
        for (int i = 0; i < np; ++i) P.pass[p].R[kk++] = (unsigned short)u[ord[i]];
        for (int i = 0; i < nrest; ++i) P.pass[p].R[kk++] = (unsigned short)u[rest[i]];
        for (int idx = 0; idx < 16; ++idx)
            P.pass[p].cmb[idx] = (unsigned short)gf_apply(Cm, raw[p].cmb[idx]);
        for (int q = 0; q < 4; ++q) P.pass[p].gidx[q] = raw[p].gidx[q];
        P.pass[p].nw = raw[p].nw;
        P.pass[p]._pad = 0;
    }
    // measurement masks: par(sigma^{-1}(t) & ms) = par(t & sigma^{-T} ms)
    for (int w = 0; w < NQ; ++w) {
        unsigned msp = 0;
        for (int i = 0; i < NQ; ++i)
            msp |= (unsigned)(par16(Ci[i] & msIdx[w]) & 1) << i;
        P.ms[w] = (unsigned short)msp;
    }

    qsim_kernel<<<dim3(B), dim3(BT), 0, stream>>>(x, qw, wl, bl, out, P);
}